// Round 4
// baseline (634.001 us; speedup 1.0000x reference)
//
#include <hip/hip_runtime.h>
#include <hip/hip_bf16.h>
#include <math.h>

typedef __attribute__((ext_vector_type(8))) short short8;
typedef __attribute__((ext_vector_type(4))) float f32x4;

#define DIM 256
#define NROWS 32768      // T*B*Ltot rows
#define PERT 2097152     // B*Ltot*D elements per timestep
#define SAMP_TOK 4096    // tokens per (t,b) sample

__device__ __forceinline__ float b2f(__hip_bfloat16 h){ return __bfloat162float(h); }
__device__ __forceinline__ __hip_bfloat16 f2b(float f){ return __float2bfloat16(f); }
__device__ __forceinline__ unsigned short f2bu(float f){
  __hip_bfloat16 h = __float2bfloat16(f);
  unsigned short u; __builtin_memcpy(&u, &h, 2); return u;
}

// load 32 bf16 (64B, 16B-aligned) -> 32 floats
__device__ __forceinline__ void load32(const __hip_bfloat16* p, float* o){
  const uint4* p4 = reinterpret_cast<const uint4*>(p);
  #pragma unroll
  for (int i = 0; i < 4; ++i){
    uint4 u = p4[i];
    unsigned w[4] = {u.x, u.y, u.z, u.w};
    #pragma unroll
    for (int j = 0; j < 4; ++j){
      o[i*8 + j*2 + 0] = __uint_as_float(w[j] << 16);
      o[i*8 + j*2 + 1] = __uint_as_float(w[j] & 0xffff0000u);
    }
  }
}

// ---------------- fp32 -> bf16 weight conversion -------------------------------
__global__ void f2b_k(const float* __restrict__ in, __hip_bfloat16* __restrict__ out, int n){
  int i = blockIdx.x * 256 + threadIdx.x;
  if (i < n) out[i] = f2b(in[i]);
}

// ---------------- BN stats: per-channel sum / sumsq over 32768 tokens ----------
__global__ void bn_stats_k(const float* __restrict__ x, float* __restrict__ sum, float* __restrict__ sumsq){
  int c = threadIdx.x;                       // channel
  size_t base = (size_t)blockIdx.x * 256 * DIM + c;   // 256 tokens per block
  float s = 0.f, s2 = 0.f;
  for (int i = 0; i < 256; ++i){
    float v = x[base + (size_t)i * DIM];
    s += v; s2 += v * v;
  }
  atomicAdd(&sum[c], s);
  atomicAdd(&sumsq[c], s2);
}

__global__ void bn_fin_k(const float* __restrict__ sum, const float* __restrict__ sumsq,
                         const float* __restrict__ g, const float* __restrict__ b,
                         float* __restrict__ a_out, float* __restrict__ b_out){
  int c = threadIdx.x;
  float mean = sum[c] * (1.f/32768.f);
  float var  = sumsq[c] * (1.f/32768.f) - mean*mean;
  float a = g[c] / sqrtf(var + 1e-5f);
  a_out[c] = a;
  b_out[c] = b[c] - mean * a;
}

// ---------------- LIF over T=4 (binary spike out, bf16 exact) ------------------
__global__ void lif_k(const float* __restrict__ x, const float* __restrict__ av,
                      const float* __restrict__ bv, __hip_bfloat16* __restrict__ s){
  int e = blockIdx.x * blockDim.x + threadIdx.x;
  if (e >= PERT) return;
  int c = e & (DIM - 1);
  float a = av[c], b = bv[c];
  float v = 0.f;
  #pragma unroll
  for (int t = 0; t < 4; ++t){
    float xn = x[(size_t)t * PERT + e] * a + b;
    v += (xn - v) * 0.5f;                 // v + (x - v)/tau, tau=2 (exact /2)
    float sp = (v >= 1.0f) ? 1.0f : 0.0f;
    s[(size_t)t * PERT + e] = f2b(sp);
    v = (v >= 1.0f) ? 0.f : v;            // hard reset
  }
}

// ---------------- region means of binary s1 (exact fp32) -----------------------
__global__ void region_sum_k(const __hip_bfloat16* __restrict__ s, float* __restrict__ sm){
  int r = blockIdx.x, c = threadIdx.x;    // r = (sample*64 + region), 512 total
  float acc = 0.f;
  size_t base = (size_t)r * 64 * DIM + c;
  for (int i = 0; i < 64; ++i) acc += b2f(s[base + (size_t)i * DIM]);
  sm[(size_t)r * DIM + c] = acc * 0.015625f;   // integer<=64 / 64: exact
}

// ---------------- routing GEMM fp32: qkm[r][j] = smr[r]·qkv_w[j] + b[j], j<512 -
__global__ void rgemm_k(const float* __restrict__ smr, const float* __restrict__ w,
                        const float* __restrict__ bias, float* __restrict__ qkm){
  __shared__ float arow[256];
  int r = blockIdx.x, t = threadIdx.x;
  arow[t] = smr[(size_t)r * 256 + t];
  __syncthreads();
  for (int j = t; j < 512; j += 256){
    const float* wr = w + (size_t)j * 256;
    float acc = 0.f;
    for (int k = 0; k < 256; ++k) acc += arow[k] * wr[k];
    qkm[(size_t)r * 512 + j] = acc + bias[j];
  }
}

// ---------------- GEMM: C[M,N] = A[M,K] @ W[N,K]^T (+bias, epilogue) -----------
// EPI 0: bf16 out = v+bias                  (qkv)
// EPI 1: f32  out = x_f32 + v*scale         (proj + residual -> x2 in d_out)
// EPI 2: bf16 out = gelu_exact(v+bias)      (ffn1)
// EPI 3: f32  out = x2_f32 + v*scale        (ffn2 + residual, in-place on d_out)
template<int EPI>
__global__ __launch_bounds__(256) void gemm_bt(
    const __hip_bfloat16* __restrict__ A, const __hip_bfloat16* __restrict__ W,
    const float* __restrict__ bias, void* __restrict__ outp,
    const void* __restrict__ extra, const float* __restrict__ scaleptr,
    int K, int N)
{
  const int LDT = 40;   // 32 + 8 pad (shorts); row stride 80B, 16B-aligned
  __shared__ __align__(16) short As[128 * 40];
  __shared__ __align__(16) short Ws[128 * 40];
  int tid = threadIdx.x;
  int bm = blockIdx.x, bn = blockIdx.y;
  int srow = tid >> 2;
  int scol = (tid & 3) << 3;
  int lane = tid & 63;
  int l16 = lane & 15, quad = lane >> 4;
  int wv = tid >> 6;
  int wm = (wv >> 1) << 6, wn = (wv & 1) << 6;

  f32x4 zero = {0.f, 0.f, 0.f, 0.f};
  f32x4 acc[4][4];
  #pragma unroll
  for (int i = 0; i < 4; ++i)
    #pragma unroll
    for (int j = 0; j < 4; ++j) acc[i][j] = zero;

  for (int k0 = 0; k0 < K; k0 += 32){
    #pragma unroll
    for (int p = 0; p < 2; ++p){
      int r = (p << 6) + srow;
      *reinterpret_cast<uint4*>(&As[r * LDT + scol]) =
        *reinterpret_cast<const uint4*>(A + (size_t)(bm * 128 + r) * K + k0 + scol);
      *reinterpret_cast<uint4*>(&Ws[r * LDT + scol]) =
        *reinterpret_cast<const uint4*>(W + (size_t)(bn * 128 + r) * K + k0 + scol);
    }
    __syncthreads();
    short8 af[4];
    #pragma unroll
    for (int mi = 0; mi < 4; ++mi)
      af[mi] = *reinterpret_cast<const short8*>(&As[(wm + mi * 16 + l16) * LDT + (quad << 3)]);
    #pragma unroll
    for (int ni = 0; ni < 4; ++ni){
      short8 bfr = *reinterpret_cast<const short8*>(&Ws[(wn + ni * 16 + l16) * LDT + (quad << 3)]);
      #pragma unroll
      for (int mi = 0; mi < 4; ++mi)
        acc[mi][ni] = __builtin_amdgcn_mfma_f32_16x16x32_bf16(af[mi], bfr, acc[mi][ni], 0, 0, 0);
    }
    __syncthreads();
  }

  float sc = 0.f;
  if (EPI == 1 || EPI == 3) sc = scaleptr[0];
  #pragma unroll
  for (int ni = 0; ni < 4; ++ni){
    int colg = (bn << 7) + wn + ni * 16 + l16;
    float bvl = bias[colg];
    #pragma unroll
    for (int mi = 0; mi < 4; ++mi){
      #pragma unroll
      for (int r = 0; r < 4; ++r){
        int rowg = (bm << 7) + wm + mi * 16 + (quad << 2) + r;   // C/D: row=quad*4+reg, col=lane&15
        float v = acc[mi][ni][r] + bvl;
        size_t off = (size_t)rowg * N + colg;
        if (EPI == 0){
          ((__hip_bfloat16*)outp)[off] = f2b(v);
        } else if (EPI == 1){
          ((float*)outp)[off] = ((const float*)extra)[off] + v * sc;
        } else if (EPI == 2){
          float gl = 0.5f * v * (1.0f + erff(v * 0.70710678118654752f));
          ((__hip_bfloat16*)outp)[off] = f2b(gl);
        } else {
          ((float*)outp)[off] = ((const float*)extra)[off] + v * sc;
        }
      }
    }
  }
}

// ---------------- top-k routing: aff = qm @ km^T per sample, pick top-4 --------
__global__ void topk_k(const float* __restrict__ qkm, int* __restrict__ idx){
  __shared__ float aff[64];
  int r = blockIdx.x;           // sample*64 + query region
  int m = threadIdx.x;          // candidate region 0..63
  int b = r >> 6;
  const float4* qrow = reinterpret_cast<const float4*>(qkm + (size_t)r * 512);
  const float4* krow = reinterpret_cast<const float4*>(qkm + (size_t)(b * 64 + m) * 512 + 256);
  float dot = 0.f;
  for (int d = 0; d < 64; ++d){
    float4 qv = qrow[d], kv = krow[d];
    dot += qv.x * kv.x + qv.y * kv.y + qv.z * kv.z + qv.w * kv.w;
  }
  aff[m] = dot;
  __syncthreads();
  if (m == 0){
    #pragma unroll
    for (int t = 0; t < 4; ++t){
      float best = -INFINITY; int bi = 0;
      for (int i = 0; i < 64; ++i){
        if (aff[i] > best){ best = aff[i]; bi = i; }   // strict >: lowest index on ties (jax top_k)
      }
      aff[bi] = -INFINITY;
      idx[r * 4 + t] = bi;
    }
  }
}

// ---------------- routed attention: block per (sample,region), wave per head ---
// qkv and o_out indexed LOCALLY (chunk of samples); idx indexed GLOBALLY (rbase).
__global__ __launch_bounds__(512) void attn_k(
    const __hip_bfloat16* __restrict__ qkv, const int* __restrict__ idx,
    __hip_bfloat16* __restrict__ o_out, int rbase)
{
  int rl = blockIdx.x;          // local region index in this chunk
  int rg = rbase + rl;          // global region index
  int bl = rl >> 6;             // local sample
  int h = threadIdx.x >> 6;     // head 0..7
  int q = threadIdx.x & 63;     // query token in region
  float qv[32];
  load32(qkv + ((size_t)rl * 64 + q) * 768 + h * 32, qv);
  float m = -INFINITY, den = 0.f;
  float o[32];
  #pragma unroll
  for (int d = 0; d < 32; ++d) o[d] = 0.f;

  for (int jr = 0; jr < 4; ++jr){
    int reg = idx[rg * 4 + jr] & 63;   // clamp: never OOB
    const __hip_bfloat16* kbase = qkv + ((size_t)bl * SAMP_TOK + (size_t)reg * 64) * 768 + 256 + h * 32;
    for (int jt = 0; jt < 64; ++jt){
      float kf[32];
      load32(kbase + (size_t)jt * 768, kf);
      float dot = 0.f;
      #pragma unroll
      for (int d = 0; d < 32; ++d) dot += qv[d] * kf[d];
      float l = dot * 0.17677669529663687f;   // 1/sqrt(32)
      float vf[32];
      load32(kbase + 256 + (size_t)jt * 768, vf);
      if (l <= m){
        float p = __expf(l - m);
        den += p;
        #pragma unroll
        for (int d = 0; d < 32; ++d) o[d] += p * vf[d];
      } else {
        float cc = __expf(m - l);
        den = den * cc + 1.f;
        #pragma unroll
        for (int d = 0; d < 32; ++d) o[d] = o[d] * cc + vf[d];
        m = l;
      }
    }
  }
  float inv = 1.f / den;
  unsigned pk[16];
  #pragma unroll
  for (int i = 0; i < 16; ++i)
    pk[i] = (unsigned)f2bu(o[2*i] * inv) | ((unsigned)f2bu(o[2*i + 1] * inv) << 16);
  uint4* dst = reinterpret_cast<uint4*>(o_out + ((size_t)rl * 64 + q) * 256 + h * 32);
  #pragma unroll
  for (int i = 0; i < 4; ++i)
    dst[i] = make_uint4(pk[4*i], pk[4*i + 1], pk[4*i + 2], pk[4*i + 3]);
}

// -------------------------------------------------------------------------------
// STRICT ws budget (never write beyond ws_size):
//   [0,4MB)   misc: BN sums/coeffs, idxb, smr, qkm, bf16 weights
//   [4,20MB)  s1 (branch1) then s2 (branch2), bf16 16MB
//   [20MB,..) chunk buffers, adaptively sized from ws_size:
//             branch1: qkv chunk (nc*6MB) + o chunk (nc*2MB), nc in {1,2,4,8}
//             branch2: h1 chunk (crows*2KB), crows power-of-2 <= 32768
// x2 (fp32 [32768,256], 32MB) lives in d_out; ffn2 updates d_out in place.
// Minimum ws_size supported: 28MB.
extern "C" void kernel_launch(void* const* d_in, const int* in_sizes, int n_in,
                              void* d_out, int out_size, void* d_ws, size_t ws_size,
                              hipStream_t stream)
{
  const float* x      = (const float*)d_in[0];
  const float* bn1_g  = (const float*)d_in[1];
  const float* bn1_b  = (const float*)d_in[2];
  const float* bn2_g  = (const float*)d_in[3];
  const float* bn2_b  = (const float*)d_in[4];
  const float* qkv_w  = (const float*)d_in[5];
  const float* qkv_b  = (const float*)d_in[6];
  const float* proj_w = (const float*)d_in[7];
  const float* proj_b = (const float*)d_in[8];
  const float* ffn_w1 = (const float*)d_in[9];
  const float* ffn_b1 = (const float*)d_in[10];
  const float* ffn_w2 = (const float*)d_in[11];
  const float* ffn_b2 = (const float*)d_in[12];
  const float* scale  = (const float*)d_in[13];
  float* x2 = (float*)d_out;       // residual lives in d_out

  char* ws = (char*)d_ws;
  const size_t MB = 1024 * 1024;
  // misc block [0,4MB)
  float* sum1 = (float*)(ws + 0);
  float* sq1  = (float*)(ws + 1024);
  float* sum2 = (float*)(ws + 2048);
  float* sq2  = (float*)(ws + 3072);
  float* a1   = (float*)(ws + 4096);
  float* b1   = (float*)(ws + 5120);
  float* a2   = (float*)(ws + 6144);
  float* b2   = (float*)(ws + 7168);
  int*   idxb = (int*)(ws + 8192);                              // 8KB
  float* smr  = (float*)(ws + 16384);                           // 512KB
  float* qkm  = (float*)(ws + 540672);                          // 1MB
  __hip_bfloat16* qkv_wb  = (__hip_bfloat16*)(ws + 1589248);    // 384KB
  __hip_bfloat16* proj_wb = (__hip_bfloat16*)(ws + 1982464);    // 128KB
  __hip_bfloat16* ffn_w1b = (__hip_bfloat16*)(ws + 2113536);    // 512KB
  __hip_bfloat16* ffn_w2b = (__hip_bfloat16*)(ws + 2637824);    // 512KB, ends 3162112 < 4MB
  __hip_bfloat16* s1 = (__hip_bfloat16*)(ws + 4 * MB);          // 16MB (s2 reuses)
  __hip_bfloat16* s2 = s1;
  char* chunkbuf = ws + 20 * MB;

  // adaptive chunk sizes from ws_size (constant across calls -> graph-safe)
  size_t avail = (ws_size > 20 * MB) ? (ws_size - 20 * MB) : (8 * MB);
  int nc = (avail >= 64 * MB) ? 8 : (avail >= 32 * MB) ? 4 : (avail >= 16 * MB) ? 2 : 1;   // samples/chunk (8MB each)
  int crows = 32768;
  while ((size_t)crows * 2048 > avail && crows > 2048) crows >>= 1;                         // ffn rows/chunk

  __hip_bfloat16* qkvc = (__hip_bfloat16*)chunkbuf;                        // nc*6MB
  __hip_bfloat16* oc   = (__hip_bfloat16*)(chunkbuf + (size_t)nc * 6 * MB); // nc*2MB
  __hip_bfloat16* h1   = (__hip_bfloat16*)chunkbuf;                        // crows*2KB

  hipMemsetAsync(d_ws, 0, 4096, stream);   // zero BN accumulators

  // one-time weight conversions fp32 -> bf16
  f2b_k<<<(196608 + 255) / 256, 256, 0, stream>>>(qkv_w, qkv_wb, 196608);
  f2b_k<<<(65536 + 255) / 256, 256, 0, stream>>>(proj_w, proj_wb, 65536);
  f2b_k<<<(262144 + 255) / 256, 256, 0, stream>>>(ffn_w1, ffn_w1b, 262144);
  f2b_k<<<(262144 + 255) / 256, 256, 0, stream>>>(ffn_w2, ffn_w2b, 262144);

  // branch 1: BN -> LIF -> routing, then per-chunk qkv -> attn -> proj+residual
  bn_stats_k<<<128, 256, 0, stream>>>(x, sum1, sq1);
  bn_fin_k<<<1, 256, 0, stream>>>(sum1, sq1, bn1_g, bn1_b, a1, b1);
  lif_k<<<PERT / 256, 256, 0, stream>>>(x, a1, b1, s1);
  region_sum_k<<<512, 256, 0, stream>>>(s1, smr);
  rgemm_k<<<512, 256, 0, stream>>>(smr, qkv_w, qkv_b, qkm);   // fp32 routing (flip-proof)
  topk_k<<<512, 64, 0, stream>>>(qkm, idxb);

  const int nchunkA = 8 / nc;
  for (int c = 0; c < nchunkA; ++c){
    const size_t ro = (size_t)c * nc * SAMP_TOK;            // row offset (tokens)
    gemm_bt<0><<<dim3(nc * SAMP_TOK / 128, 6), 256, 0, stream>>>(
        s1 + ro * 256, qkv_wb, qkv_b, qkvc, nullptr, nullptr, 256, 768);
    attn_k<<<nc * 64, 512, 0, stream>>>(qkvc, idxb, oc, c * nc * 64);
    gemm_bt<1><<<dim3(nc * SAMP_TOK / 128, 2), 256, 0, stream>>>(
        oc, proj_wb, proj_b, x2 + ro * 256, x + ro * 256, scale, 256, 256);
  }

  // branch 2: BN -> LIF -> FFN(gelu) + residual (in-place on d_out)
  bn_stats_k<<<128, 256, 0, stream>>>(x2, sum2, sq2);
  bn_fin_k<<<1, 256, 0, stream>>>(sum2, sq2, bn2_g, bn2_b, a2, b2);
  lif_k<<<PERT / 256, 256, 0, stream>>>(x2, a2, b2, s2);
  const int nchunkF = 32768 / crows;
  for (int c = 0; c < nchunkF; ++c){
    const size_t ro = (size_t)c * crows;
    gemm_bt<2><<<dim3(crows / 128, 8), 256, 0, stream>>>(
        s2 + ro * 256, ffn_w1b, ffn_b1, h1, nullptr, nullptr, 256, 1024);
    gemm_bt<3><<<dim3(crows / 128, 2), 256, 0, stream>>>(
        h1, ffn_w2b, ffn_b2, x2 + ro * 256, x2 + ro * 256, scale, 1024, 256);
  }
}

// Round 5
// 383.058 us; speedup vs baseline: 1.6551x; 1.6551x over previous
//
#include <hip/hip_runtime.h>
#include <hip/hip_bf16.h>
#include <math.h>

typedef __attribute__((ext_vector_type(8))) short short8;
typedef __attribute__((ext_vector_type(4))) float f32x4;

#define DIM 256
#define NROWS 32768      // T*B*Ltot rows
#define PERT 2097152     // B*Ltot*D elements per timestep
#define SAMP_TOK 4096    // tokens per (t,b) sample

__device__ __forceinline__ float b2f(__hip_bfloat16 h){ return __bfloat162float(h); }
__device__ __forceinline__ __hip_bfloat16 f2b(float f){ return __float2bfloat16(f); }
__device__ __forceinline__ unsigned short f2bu(float f){
  __hip_bfloat16 h = __float2bfloat16(f);
  unsigned short u; __builtin_memcpy(&u, &h, 2); return u;
}

// ---------------- fp32 -> bf16 weight conversion -------------------------------
__global__ void f2b_k(const float* __restrict__ in, __hip_bfloat16* __restrict__ out, int n){
  int i = blockIdx.x * 256 + threadIdx.x;
  if (i < n) out[i] = f2b(in[i]);
}

// ---------------- BN stats: per-channel sum / sumsq over 32768 tokens ----------
__global__ void bn_stats_k(const float* __restrict__ x, float* __restrict__ sum, float* __restrict__ sumsq){
  int c = threadIdx.x;                       // channel
  size_t base = (size_t)blockIdx.x * 256 * DIM + c;   // 256 tokens per block
  float s = 0.f, s2 = 0.f;
  for (int i = 0; i < 256; ++i){
    float v = x[base + (size_t)i * DIM];
    s += v; s2 += v * v;
  }
  atomicAdd(&sum[c], s);
  atomicAdd(&sumsq[c], s2);
}

__global__ void bn_fin_k(const float* __restrict__ sum, const float* __restrict__ sumsq,
                         const float* __restrict__ g, const float* __restrict__ b,
                         float* __restrict__ a_out, float* __restrict__ b_out){
  int c = threadIdx.x;
  float mean = sum[c] * (1.f/32768.f);
  float var  = sumsq[c] * (1.f/32768.f) - mean*mean;
  float a = g[c] / sqrtf(var + 1e-5f);
  a_out[c] = a;
  b_out[c] = b[c] - mean * a;
}

// ---------------- LIF over T=4 (binary spike out, bf16 exact) ------------------
__global__ void lif_k(const float* __restrict__ x, const float* __restrict__ av,
                      const float* __restrict__ bv, __hip_bfloat16* __restrict__ s){
  int e = blockIdx.x * blockDim.x + threadIdx.x;
  if (e >= PERT) return;
  int c = e & (DIM - 1);
  float a = av[c], b = bv[c];
  float v = 0.f;
  #pragma unroll
  for (int t = 0; t < 4; ++t){
    float xn = x[(size_t)t * PERT + e] * a + b;
    v += (xn - v) * 0.5f;                 // v + (x - v)/tau, tau=2 (exact /2)
    float sp = (v >= 1.0f) ? 1.0f : 0.0f;
    s[(size_t)t * PERT + e] = f2b(sp);
    v = (v >= 1.0f) ? 0.f : v;            // hard reset
  }
}

// ---------------- region means of binary s1 (exact fp32) -----------------------
__global__ void region_sum_k(const __hip_bfloat16* __restrict__ s, float* __restrict__ sm){
  int r = blockIdx.x, c = threadIdx.x;    // r = (sample*64 + region), 512 total
  float acc = 0.f;
  size_t base = (size_t)r * 64 * DIM + c;
  for (int i = 0; i < 64; ++i) acc += b2f(s[base + (size_t)i * DIM]);
  sm[(size_t)r * DIM + c] = acc * 0.015625f;   // integer<=64 / 64: exact
}

// ---------------- routing GEMM fp32: qkm[r][j] = smr[r]·qkv_w[j] + b[j], j<512 -
__global__ void rgemm_k(const float* __restrict__ smr, const float* __restrict__ w,
                        const float* __restrict__ bias, float* __restrict__ qkm){
  __shared__ float arow[256];
  int r = blockIdx.x, t = threadIdx.x;
  arow[t] = smr[(size_t)r * 256 + t];
  __syncthreads();
  for (int j = t; j < 512; j += 256){
    const float* wr = w + (size_t)j * 256;
    float acc = 0.f;
    for (int k = 0; k < 256; ++k) acc += arow[k] * wr[k];
    qkm[(size_t)r * 512 + j] = acc + bias[j];
  }
}

// ---------------- GEMM: C[M,N] = A[M,K] @ W[N,K]^T (+bias, epilogue) -----------
// EPI 0: bf16 out = v+bias                  (qkv)
// EPI 1: f32  out = x_f32 + v*scale         (proj + residual -> x2 in d_out)
// EPI 2: bf16 out = gelu_exact(v+bias)      (ffn1)
// EPI 3: f32  out = x2_f32 + v*scale        (ffn2 + residual, in-place on d_out)
template<int EPI>
__global__ __launch_bounds__(256) void gemm_bt(
    const __hip_bfloat16* __restrict__ A, const __hip_bfloat16* __restrict__ W,
    const float* __restrict__ bias, void* __restrict__ outp,
    const void* __restrict__ extra, const float* __restrict__ scaleptr,
    int K, int N)
{
  const int LDT = 40;   // 32 + 8 pad (shorts); row stride 80B, 16B-aligned
  __shared__ __align__(16) short As[128 * 40];
  __shared__ __align__(16) short Ws[128 * 40];
  int tid = threadIdx.x;
  int bm = blockIdx.x, bn = blockIdx.y;
  int srow = tid >> 2;
  int scol = (tid & 3) << 3;
  int lane = tid & 63;
  int l16 = lane & 15, quad = lane >> 4;
  int wv = tid >> 6;
  int wm = (wv >> 1) << 6, wn = (wv & 1) << 6;

  f32x4 zero = {0.f, 0.f, 0.f, 0.f};
  f32x4 acc[4][4];
  #pragma unroll
  for (int i = 0; i < 4; ++i)
    #pragma unroll
    for (int j = 0; j < 4; ++j) acc[i][j] = zero;

  for (int k0 = 0; k0 < K; k0 += 32){
    #pragma unroll
    for (int p = 0; p < 2; ++p){
      int r = (p << 6) + srow;
      *reinterpret_cast<uint4*>(&As[r * LDT + scol]) =
        *reinterpret_cast<const uint4*>(A + (size_t)(bm * 128 + r) * K + k0 + scol);
      *reinterpret_cast<uint4*>(&Ws[r * LDT + scol]) =
        *reinterpret_cast<const uint4*>(W + (size_t)(bn * 128 + r) * K + k0 + scol);
    }
    __syncthreads();
    short8 af[4];
    #pragma unroll
    for (int mi = 0; mi < 4; ++mi)
      af[mi] = *reinterpret_cast<const short8*>(&As[(wm + mi * 16 + l16) * LDT + (quad << 3)]);
    #pragma unroll
    for (int ni = 0; ni < 4; ++ni){
      short8 bfr = *reinterpret_cast<const short8*>(&Ws[(wn + ni * 16 + l16) * LDT + (quad << 3)]);
      #pragma unroll
      for (int mi = 0; mi < 4; ++mi)
        acc[mi][ni] = __builtin_amdgcn_mfma_f32_16x16x32_bf16(af[mi], bfr, acc[mi][ni], 0, 0, 0);
    }
    __syncthreads();
  }

  float sc = 0.f;
  if (EPI == 1 || EPI == 3) sc = scaleptr[0];
  #pragma unroll
  for (int ni = 0; ni < 4; ++ni){
    int colg = (bn << 7) + wn + ni * 16 + l16;
    float bvl = bias[colg];
    #pragma unroll
    for (int mi = 0; mi < 4; ++mi){
      #pragma unroll
      for (int r = 0; r < 4; ++r){
        int rowg = (bm << 7) + wm + mi * 16 + (quad << 2) + r;   // C/D: row=quad*4+reg, col=lane&15
        float v = acc[mi][ni][r] + bvl;
        size_t off = (size_t)rowg * N + colg;
        if (EPI == 0){
          ((__hip_bfloat16*)outp)[off] = f2b(v);
        } else if (EPI == 1){
          ((float*)outp)[off] = ((const float*)extra)[off] + v * sc;
        } else if (EPI == 2){
          float gl = 0.5f * v * (1.0f + erff(v * 0.70710678118654752f));
          ((__hip_bfloat16*)outp)[off] = f2b(gl);
        } else {
          ((float*)outp)[off] = ((const float*)extra)[off] + v * sc;
        }
      }
    }
  }
}

// ---------------- top-k routing: aff = qm @ km^T per sample, pick top-4 --------
__global__ void topk_k(const float* __restrict__ qkm, int* __restrict__ idx){
  __shared__ float aff[64];
  int r = blockIdx.x;           // sample*64 + query region
  int m = threadIdx.x;          // candidate region 0..63
  int b = r >> 6;
  const float4* qrow = reinterpret_cast<const float4*>(qkm + (size_t)r * 512);
  const float4* krow = reinterpret_cast<const float4*>(qkm + (size_t)(b * 64 + m) * 512 + 256);
  float dot = 0.f;
  for (int d = 0; d < 64; ++d){
    float4 qv = qrow[d], kv = krow[d];
    dot += qv.x * kv.x + qv.y * kv.y + qv.z * kv.z + qv.w * kv.w;
  }
  aff[m] = dot;
  __syncthreads();
  if (m == 0){
    #pragma unroll
    for (int t = 0; t < 4; ++t){
      float best = -INFINITY; int bi = 0;
      for (int i = 0; i < 64; ++i){
        if (aff[i] > best){ best = aff[i]; bi = i; }   // strict >: lowest index on ties (jax top_k)
      }
      aff[bi] = -INFINITY;
      idx[r * 4 + t] = bi;
    }
  }
}

// ---------------- MFMA routed attention: block per (region, head) --------------
// 256 threads = 4 waves; wave w owns q rows [w*16, w*16+16).
// LDS: Ks[256][40] (20480B) -> aliased by Vt[32][264] (16896B) after S;
//      P per wave [16][264] bf16 at short-offset 10240 + w*4224. Total 54272B.
__global__ __launch_bounds__(256) void attn_mfma_k(
    const __hip_bfloat16* __restrict__ qkv, const int* __restrict__ idx,
    __hip_bfloat16* __restrict__ o_out, int rbase)
{
  __shared__ __align__(16) short lds[27136];
  __shared__ float den_s[4][16];
  const int rl = blockIdx.x;       // local region in this chunk
  const int h  = blockIdx.y;       // head
  const int rg = rbase + rl;       // global region (for idx)
  const int bl = rl >> 6;          // local sample
  const int tid = threadIdx.x;
  const int w = tid >> 6, lane = tid & 63;
  const int l16 = lane & 15, quad = lane >> 4;
  short* Pw = lds + 10240 + w * 4224;

  // --- staging: thread tid handles gathered token tid (4 regions x 64) ---
  const int reg = idx[rg * 4 + (tid >> 6)] & 63;       // clamp: never OOB
  const size_t srow = (size_t)bl * SAMP_TOK + (size_t)reg * 64 + (tid & 63);
  const __hip_bfloat16* kvsrc = qkv + srow * 768 + 256 + (size_t)h * 32;

  // Q fragment (A-layout): lane m=l16 -> q row w*16+l16; k-elems quad*8..+7
  const size_t qrow = (size_t)rl * 64 + w * 16 + l16;
  short8 qf = *reinterpret_cast<const short8*>(qkv + qrow * 768 + (size_t)h * 32 + quad * 8);

  // V into registers now (LDS write deferred until K is dead)
  uint4 vreg[4];
  #pragma unroll
  for (int c = 0; c < 4; ++c)
    vreg[c] = *reinterpret_cast<const uint4*>(kvsrc + 256 + c * 8);

  // K -> Ks[token][40]
  #pragma unroll
  for (int c = 0; c < 4; ++c)
    *reinterpret_cast<uint4*>(&lds[tid * 40 + c * 8]) =
      *reinterpret_cast<const uint4*>(kvsrc + c * 8);
  __syncthreads();

  // --- S = Q K^T : 16 N-tiles (k-tokens), K-dim 32 = head dim, one MFMA each ---
  f32x4 s[16];
  #pragma unroll
  for (int nt = 0; nt < 16; ++nt){
    short8 bf = *reinterpret_cast<const short8*>(&lds[(nt * 16 + l16) * 40 + quad * 8]);
    f32x4 z = {0.f, 0.f, 0.f, 0.f};
    s[nt] = __builtin_amdgcn_mfma_f32_16x16x32_bf16(qf, bf, z, 0, 0, 0);
  }
  __syncthreads();   // all waves done reading Ks

  // --- write Vt[d][tok] (overwrites Ks space) ---
  #pragma unroll
  for (int c = 0; c < 4; ++c){
    short8 vv = *reinterpret_cast<short8*>(&vreg[c]);
    #pragma unroll
    for (int e = 0; e < 8; ++e)
      lds[(c * 8 + e) * 264 + tid] = vv[e];
  }

  // --- softmax over 256 cols; lane holds rows quad*4+r, cols nt*16+l16 ---
  float m4[4] = {-1e30f, -1e30f, -1e30f, -1e30f};
  #pragma unroll
  for (int nt = 0; nt < 16; ++nt)
    #pragma unroll
    for (int r = 0; r < 4; ++r) m4[r] = fmaxf(m4[r], s[nt][r]);
  #pragma unroll
  for (int xm = 1; xm < 16; xm <<= 1)
    #pragma unroll
    for (int r = 0; r < 4; ++r) m4[r] = fmaxf(m4[r], __shfl_xor(m4[r], xm));
  float d4[4] = {0.f, 0.f, 0.f, 0.f};
  #pragma unroll
  for (int nt = 0; nt < 16; ++nt)
    #pragma unroll
    for (int r = 0; r < 4; ++r){
      float e = __expf((s[nt][r] - m4[r]) * 0.17677669529663687f);  // scale folded in
      s[nt][r] = e; d4[r] += e;
    }
  #pragma unroll
  for (int xm = 1; xm < 16; xm <<= 1)
    #pragma unroll
    for (int r = 0; r < 4; ++r) d4[r] += __shfl_xor(d4[r], xm);
  if (l16 == 0){
    #pragma unroll
    for (int r = 0; r < 4; ++r) den_s[w][quad * 4 + r] = d4[r];
  }
  // P bf16 row-major [16][264] for this wave (C-layout -> A/B-readable layout)
  #pragma unroll
  for (int nt = 0; nt < 16; ++nt)
    #pragma unroll
    for (int r = 0; r < 4; ++r)
      Pw[(quad * 4 + r) * 264 + nt * 16 + l16] = (short)f2bu(s[nt][r]);
  __syncthreads();

  // --- O^T = V^T P^T : M=d (2 tiles), N=q (16), K=256 (8 steps) ---
  f32x4 o0 = {0.f, 0.f, 0.f, 0.f}, o1 = o0;
  #pragma unroll
  for (int kk = 0; kk < 8; ++kk){
    short8 pb = *reinterpret_cast<const short8*>(&Pw[l16 * 264 + kk * 32 + quad * 8]);
    short8 a0 = *reinterpret_cast<const short8*>(&lds[l16 * 264 + kk * 32 + quad * 8]);
    short8 a1 = *reinterpret_cast<const short8*>(&lds[(16 + l16) * 264 + kk * 32 + quad * 8]);
    o0 = __builtin_amdgcn_mfma_f32_16x16x32_bf16(a0, pb, o0, 0, 0, 0);
    o1 = __builtin_amdgcn_mfma_f32_16x16x32_bf16(a1, pb, o1, 0, 0, 0);
  }
  // normalize + store: col(l16)=q_local, row(quad*4+r)=d; o1 tile d+16
  float inv = 1.f / den_s[w][l16];
  size_t obase = ((size_t)rl * 64 + w * 16 + l16) * 256 + (size_t)h * 32;
  unsigned pk0 = (unsigned)f2bu(o0[0] * inv) | ((unsigned)f2bu(o0[1] * inv) << 16);
  unsigned pk1 = (unsigned)f2bu(o0[2] * inv) | ((unsigned)f2bu(o0[3] * inv) << 16);
  unsigned pk2 = (unsigned)f2bu(o1[0] * inv) | ((unsigned)f2bu(o1[1] * inv) << 16);
  unsigned pk3 = (unsigned)f2bu(o1[2] * inv) | ((unsigned)f2bu(o1[3] * inv) << 16);
  *reinterpret_cast<uint2*>(o_out + obase + quad * 4)      = make_uint2(pk0, pk1);
  *reinterpret_cast<uint2*>(o_out + obase + 16 + quad * 4) = make_uint2(pk2, pk3);
}

// -------------------------------------------------------------------------------
// STRICT ws budget (never write beyond ws_size):
//   [0,4MB)   misc: BN sums/coeffs, idxb, smr, qkm, bf16 weights
//   [4,20MB)  s1 (branch1) then s2 (branch2), bf16 16MB
//   [20MB,..) chunk buffers, adaptively sized from ws_size:
//             branch1: qkv chunk (nc*6MB) + o chunk (nc*2MB), nc in {1,2,4,8}
//             branch2: h1 chunk (crows*2KB), crows power-of-2 <= 32768
// x2 (fp32 [32768,256], 32MB) lives in d_out; ffn2 updates d_out in place.
// Minimum ws_size supported: 28MB.
extern "C" void kernel_launch(void* const* d_in, const int* in_sizes, int n_in,
                              void* d_out, int out_size, void* d_ws, size_t ws_size,
                              hipStream_t stream)
{
  const float* x      = (const float*)d_in[0];
  const float* bn1_g  = (const float*)d_in[1];
  const float* bn1_b  = (const float*)d_in[2];
  const float* bn2_g  = (const float*)d_in[3];
  const float* bn2_b  = (const float*)d_in[4];
  const float* qkv_w  = (const float*)d_in[5];
  const float* qkv_b  = (const float*)d_in[6];
  const float* proj_w = (const float*)d_in[7];
  const float* proj_b = (const float*)d_in[8];
  const float* ffn_w1 = (const float*)d_in[9];
  const float* ffn_b1 = (const float*)d_in[10];
  const float* ffn_w2 = (const float*)d_in[11];
  const float* ffn_b2 = (const float*)d_in[12];
  const float* scale  = (const float*)d_in[13];
  float* x2 = (float*)d_out;       // residual lives in d_out

  char* ws = (char*)d_ws;
  const size_t MB = 1024 * 1024;
  // misc block [0,4MB)
  float* sum1 = (float*)(ws + 0);
  float* sq1  = (float*)(ws + 1024);
  float* sum2 = (float*)(ws + 2048);
  float* sq2  = (float*)(ws + 3072);
  float* a1   = (float*)(ws + 4096);
  float* b1   = (float*)(ws + 5120);
  float* a2   = (float*)(ws + 6144);
  float* b2   = (float*)(ws + 7168);
  int*   idxb = (int*)(ws + 8192);                              // 8KB
  float* smr  = (float*)(ws + 16384);                           // 512KB
  float* qkm  = (float*)(ws + 540672);                          // 1MB
  __hip_bfloat16* qkv_wb  = (__hip_bfloat16*)(ws + 1589248);    // 384KB
  __hip_bfloat16* proj_wb = (__hip_bfloat16*)(ws + 1982464);    // 128KB
  __hip_bfloat16* ffn_w1b = (__hip_bfloat16*)(ws + 2113536);    // 512KB
  __hip_bfloat16* ffn_w2b = (__hip_bfloat16*)(ws + 2637824);    // 512KB, ends 3162112 < 4MB
  __hip_bfloat16* s1 = (__hip_bfloat16*)(ws + 4 * MB);          // 16MB (s2 reuses)
  __hip_bfloat16* s2 = s1;
  char* chunkbuf = ws + 20 * MB;

  // adaptive chunk sizes from ws_size (constant across calls -> graph-safe)
  size_t avail = (ws_size > 20 * MB) ? (ws_size - 20 * MB) : (8 * MB);
  int nc = (avail >= 64 * MB) ? 8 : (avail >= 32 * MB) ? 4 : (avail >= 16 * MB) ? 2 : 1;   // samples/chunk (8MB each)
  int crows = 32768;
  while ((size_t)crows * 2048 > avail && crows > 2048) crows >>= 1;                         // ffn rows/chunk

  __hip_bfloat16* qkvc = (__hip_bfloat16*)chunkbuf;                        // nc*6MB
  __hip_bfloat16* oc   = (__hip_bfloat16*)(chunkbuf + (size_t)nc * 6 * MB); // nc*2MB
  __hip_bfloat16* h1   = (__hip_bfloat16*)chunkbuf;                        // crows*2KB

  hipMemsetAsync(d_ws, 0, 4096, stream);   // zero BN accumulators

  // one-time weight conversions fp32 -> bf16
  f2b_k<<<(196608 + 255) / 256, 256, 0, stream>>>(qkv_w, qkv_wb, 196608);
  f2b_k<<<(65536 + 255) / 256, 256, 0, stream>>>(proj_w, proj_wb, 65536);
  f2b_k<<<(262144 + 255) / 256, 256, 0, stream>>>(ffn_w1, ffn_w1b, 262144);
  f2b_k<<<(262144 + 255) / 256, 256, 0, stream>>>(ffn_w2, ffn_w2b, 262144);

  // branch 1: BN -> LIF -> routing, then per-chunk qkv -> attn -> proj+residual
  bn_stats_k<<<128, 256, 0, stream>>>(x, sum1, sq1);
  bn_fin_k<<<1, 256, 0, stream>>>(sum1, sq1, bn1_g, bn1_b, a1, b1);
  lif_k<<<PERT / 256, 256, 0, stream>>>(x, a1, b1, s1);
  region_sum_k<<<512, 256, 0, stream>>>(s1, smr);
  rgemm_k<<<512, 256, 0, stream>>>(smr, qkv_w, qkv_b, qkm);   // fp32 routing (flip-proof)
  topk_k<<<512, 64, 0, stream>>>(qkm, idxb);

  const int nchunkA = 8 / nc;
  for (int c = 0; c < nchunkA; ++c){
    const size_t ro = (size_t)c * nc * SAMP_TOK;            // row offset (tokens)
    gemm_bt<0><<<dim3(nc * SAMP_TOK / 128, 6), 256, 0, stream>>>(
        s1 + ro * 256, qkv_wb, qkv_b, qkvc, nullptr, nullptr, 256, 768);
    attn_mfma_k<<<dim3(nc * 64, 8), 256, 0, stream>>>(qkvc, idxb, oc, c * nc * 64);
    gemm_bt<1><<<dim3(nc * SAMP_TOK / 128, 2), 256, 0, stream>>>(
        oc, proj_wb, proj_b, x2 + ro * 256, x + ro * 256, scale, 256, 256);
  }

  // branch 2: BN -> LIF -> FFN(gelu) + residual (in-place on d_out)
  bn_stats_k<<<128, 256, 0, stream>>>(x2, sum2, sq2);
  bn_fin_k<<<1, 256, 0, stream>>>(sum2, sq2, bn2_g, bn2_b, a2, b2);
  lif_k<<<PERT / 256, 256, 0, stream>>>(x2, a2, b2, s2);
  const int nchunkF = 32768 / crows;
  for (int c = 0; c < nchunkF; ++c){
    const size_t ro = (size_t)c * crows;
    gemm_bt<2><<<dim3(crows / 128, 8), 256, 0, stream>>>(
        s2 + ro * 256, ffn_w1b, ffn_b1, h1, nullptr, nullptr, 256, 1024);
    gemm_bt<3><<<dim3(crows / 128, 2), 256, 0, stream>>>(
        h1, ffn_w2b, ffn_b2, x2 + ro * 256, x2 + ro * 256, scale, 1024, 256);
  }
}